// Round 1
// baseline (871.626 us; speedup 1.0000x reference)
//
#include <hip/hip_runtime.h>

// GraphSAGE x3 + BN(train stats) + ReLU + linear head. fp32 throughout.
// ws layout: bufA/bufB/bufC [N*128]f32, deg/offs/cursor ints, esrc[E], stats.
// Total ws use ~161 MB.

#define N_NODES 100000
#define N_EDGES 1250000

// ----------------- CSR build -----------------
__global__ void k_hist(const int* __restrict__ dst, int* __restrict__ deg, int E) {
  int i = blockIdx.x * blockDim.x + threadIdx.x;
  if (i < E) atomicAdd(&deg[dst[i]], 1);
}

__global__ void k_scan1(const int* __restrict__ deg, int* __restrict__ offs,
                        int* __restrict__ bsum, int n) {
  __shared__ int sh[256];
  int t = threadIdx.x;
  int base = blockIdx.x * 1024 + t * 4;
  int v0 = (base + 0 < n) ? deg[base + 0] : 0;
  int v1 = (base + 1 < n) ? deg[base + 1] : 0;
  int v2 = (base + 2 < n) ? deg[base + 2] : 0;
  int v3 = (base + 3 < n) ? deg[base + 3] : 0;
  int s = v0 + v1 + v2 + v3;
  sh[t] = s;
  __syncthreads();
  #pragma unroll
  for (int off = 1; off < 256; off <<= 1) {
    int x = (t >= off) ? sh[t - off] : 0;
    __syncthreads();
    sh[t] += x;
    __syncthreads();
  }
  int run = sh[t] - s;  // exclusive prefix within block
  if (base + 0 < n) offs[base + 0] = run; run += v0;
  if (base + 1 < n) offs[base + 1] = run; run += v1;
  if (base + 2 < n) offs[base + 2] = run; run += v2;
  if (base + 3 < n) offs[base + 3] = run;
  if (t == 255) bsum[blockIdx.x] = sh[255];
}

__global__ void k_scan2(int* __restrict__ bsum, int nb) {
  __shared__ int sh[256];
  int t = threadIdx.x;
  int v = (t < nb) ? bsum[t] : 0;
  sh[t] = v;
  __syncthreads();
  #pragma unroll
  for (int off = 1; off < 256; off <<= 1) {
    int x = (t >= off) ? sh[t - off] : 0;
    __syncthreads();
    sh[t] += x;
    __syncthreads();
  }
  if (t < nb) bsum[t] = sh[t] - v;  // exclusive block base
}

__global__ void k_scan3(int* __restrict__ offs, int* __restrict__ cursor,
                        const int* __restrict__ bsum, int n, int E) {
  int i = blockIdx.x * blockDim.x + threadIdx.x;
  if (i < n) {
    int v = offs[i] + bsum[i >> 10];
    offs[i] = v;
    cursor[i] = v;
  }
  if (i == 0) offs[n] = E;
}

__global__ void k_scatter(const int* __restrict__ src, const int* __restrict__ dst,
                          int* __restrict__ cursor, int* __restrict__ esrc, int E) {
  int i = blockIdx.x * blockDim.x + threadIdx.x;
  if (i < E) {
    int p = atomicAdd(&cursor[dst[i]], 1);
    esrc[p] = src[i];
  }
}

// ----------------- mean aggregation (gather over CSR) -----------------
// DIM/4 threads cooperate per node; each owns one float4 of the feature row.
template <int DIM>
__global__ void k_agg(const float* __restrict__ h, const int* __restrict__ offs,
                      const int* __restrict__ esrc, float* __restrict__ neigh, int n) {
  const int G = DIM / 4;
  int tid = blockIdx.x * blockDim.x + threadIdx.x;
  int node = tid / G;
  int f = tid % G;
  if (node >= n) return;
  int s = offs[node], e = offs[node + 1];
  float4 acc = make_float4(0.f, 0.f, 0.f, 0.f);
  for (int j = s; j < e; j++) {
    int sn = esrc[j];
    float4 v = *(const float4*)&h[(size_t)sn * DIM + 4 * f];
    acc.x += v.x; acc.y += v.y; acc.z += v.z; acc.w += v.w;
  }
  float inv = 1.0f / fmaxf((float)(e - s), 1.0f);
  acc.x *= inv; acc.y *= inv; acc.z *= inv; acc.w *= inv;
  *(float4*)&neigh[(size_t)node * DIM + 4 * f] = acc;
}

// ----------------- dual-input GEMM: C = A1@W1 + A2@W2 + bias, + BN stats ---
// M x din @ din x 128 (twice). BM=64 rows/block, BK=32, 256 threads.
// Thread (tx,ty): cols {tx, tx+32, tx+64, tx+96}, rows ty*8..ty*8+7.
__global__ __launch_bounds__(256) void k_gemm2(
    const float* __restrict__ A1, const float* __restrict__ W1,
    const float* __restrict__ A2, const float* __restrict__ W2,
    const float* __restrict__ bias, float* __restrict__ C,
    float* __restrict__ stats, int M, int din) {
  __shared__ float As[32][68];   // [k][row], padded
  __shared__ float Wsh[32][128]; // [k][col]
  __shared__ float red[8][32];

  int t = threadIdx.x;
  int tx = t & 31, ty = t >> 5;
  int row0 = blockIdx.x * 64;

  float acc[8][4];
  #pragma unroll
  for (int r = 0; r < 8; r++)
    #pragma unroll
    for (int c = 0; c < 4; c++) acc[r][c] = 0.f;

  for (int half = 0; half < 2; half++) {
    const float* A = half ? A2 : A1;
    const float* W = half ? W2 : W1;
    for (int k0 = 0; k0 < din; k0 += 32) {
      // stage A tile (64 rows x 32 k), transposed into LDS
      #pragma unroll
      for (int i = 0; i < 2; i++) {
        int idx = t + 256 * i;        // 0..511 float4s
        int r = idx >> 3;
        int f4 = idx & 7;
        int row = row0 + r;
        float4 v = make_float4(0.f, 0.f, 0.f, 0.f);
        if (row < M) v = *(const float4*)&A[(size_t)row * din + k0 + 4 * f4];
        As[4 * f4 + 0][r] = v.x;
        As[4 * f4 + 1][r] = v.y;
        As[4 * f4 + 2][r] = v.z;
        As[4 * f4 + 3][r] = v.w;
      }
      // stage W tile (32 k x 128 cols)
      #pragma unroll
      for (int i = 0; i < 4; i++) {
        int idx = t + 256 * i;        // 0..1023 float4s
        int k = idx >> 5;
        int f4 = idx & 31;
        *(float4*)&Wsh[k][4 * f4] = *(const float4*)&W[(size_t)(k0 + k) * 128 + 4 * f4];
      }
      __syncthreads();
      #pragma unroll 4
      for (int k = 0; k < 32; k++) {
        float a[8];
        *(float4*)&a[0] = *(const float4*)&As[k][ty * 8];
        *(float4*)&a[4] = *(const float4*)&As[k][ty * 8 + 4];
        float w[4] = {Wsh[k][tx], Wsh[k][tx + 32], Wsh[k][tx + 64], Wsh[k][tx + 96]};
        #pragma unroll
        for (int r = 0; r < 8; r++)
          #pragma unroll
          for (int c = 0; c < 4; c++) acc[r][c] = fmaf(a[r], w[c], acc[r][c]);
      }
      __syncthreads();
    }
  }

  float b[4] = {bias[tx], bias[tx + 32], bias[tx + 64], bias[tx + 96]};
  float ls[4] = {0.f, 0.f, 0.f, 0.f}, lq[4] = {0.f, 0.f, 0.f, 0.f};
  #pragma unroll
  for (int r = 0; r < 8; r++) {
    int row = row0 + ty * 8 + r;
    if (row < M) {
      #pragma unroll
      for (int c = 0; c < 4; c++) {
        float v = acc[r][c] + b[c];
        C[(size_t)row * 128 + tx + 32 * c] = v;
        ls[c] += v;
        lq[c] += v * v;
      }
    }
  }
  // per-block column reduction -> global atomics (sum, sumsq)
  #pragma unroll
  for (int c = 0; c < 4; c++) {
    red[ty][tx] = ls[c];
    __syncthreads();
    if (ty == 0) {
      float s = 0.f;
      #pragma unroll
      for (int j = 0; j < 8; j++) s += red[j][tx];
      atomicAdd(&stats[tx + 32 * c], s);
    }
    __syncthreads();
    red[ty][tx] = lq[c];
    __syncthreads();
    if (ty == 0) {
      float s = 0.f;
      #pragma unroll
      for (int j = 0; j < 8; j++) s += red[j][tx];
      atomicAdd(&stats[128 + tx + 32 * c], s);
    }
    __syncthreads();
  }
}

// ----------------- BN finalize: s = gamma*rsqrt(var+eps), t = beta - mu*s ---
__global__ void k_bnfin(const float* __restrict__ stats, const float* __restrict__ gamma,
                        const float* __restrict__ beta, float* __restrict__ sscale,
                        float* __restrict__ sshift, float invN) {
  int c = threadIdx.x;  // 128
  float mu = stats[c] * invN;
  float var = stats[128 + c] * invN - mu * mu;
  float rs = rsqrtf(var + 1e-5f);
  float s = gamma[c] * rs;
  sscale[c] = s;
  sshift[c] = beta[c] - mu * s;
}

// ----------------- BN apply + ReLU (in place) -----------------
__global__ void k_bnrelu(float* __restrict__ h, const float* __restrict__ sscale,
                         const float* __restrict__ sshift, int total4) {
  int i = blockIdx.x * blockDim.x + threadIdx.x;
  if (i >= total4) return;
  int c4 = (i & 31) * 4;  // column of this float4
  float4 v = ((float4*)h)[i];
  float4 s = *(const float4*)&sscale[c4];
  float4 tt = *(const float4*)&sshift[c4];
  v.x = fmaxf(fmaf(v.x, s.x, tt.x), 0.f);
  v.y = fmaxf(fmaf(v.y, s.y, tt.y), 0.f);
  v.z = fmaxf(fmaf(v.z, s.z, tt.z), 0.f);
  v.w = fmaxf(fmaf(v.w, s.w, tt.w), 0.f);
  ((float4*)h)[i] = v;
}

// ----------------- fused BN + ReLU + classifier (wave per row) -----------------
__global__ void k_final(const float* __restrict__ h, const float* __restrict__ sscale,
                        const float* __restrict__ sshift, const float* __restrict__ Wc,
                        const float* __restrict__ bc, float* __restrict__ out, int n) {
  int lane = threadIdx.x & 63;
  int row = blockIdx.x * (blockDim.x >> 6) + (threadIdx.x >> 6);
  if (row >= n) return;
  float acc0 = 0.f, acc1 = 0.f;
  #pragma unroll
  for (int m = 0; m < 2; m++) {
    int c = lane + 64 * m;
    float v = h[(size_t)row * 128 + c];
    v = fmaxf(fmaf(v, sscale[c], sshift[c]), 0.f);
    acc0 += v * Wc[c * 2 + 0];
    acc1 += v * Wc[c * 2 + 1];
  }
  #pragma unroll
  for (int off = 32; off > 0; off >>= 1) {
    acc0 += __shfl_down(acc0, off);
    acc1 += __shfl_down(acc1, off);
  }
  if (lane == 0) {
    out[row * 2 + 0] = acc0 + bc[0];
    out[row * 2 + 1] = acc1 + bc[1];
  }
}

extern "C" void kernel_launch(void* const* d_in, const int* in_sizes, int n_in,
                              void* d_out, int out_size, void* d_ws, size_t ws_size,
                              hipStream_t stream) {
  const float* x   = (const float*)d_in[0];
  const int* src   = (const int*)d_in[1];
  const int* dst   = (const int*)d_in[2];
  const float* Wself[3] = {(const float*)d_in[3], (const float*)d_in[8],  (const float*)d_in[13]};
  const float* bself[3] = {(const float*)d_in[4], (const float*)d_in[9],  (const float*)d_in[14]};
  const float* Wngh[3]  = {(const float*)d_in[5], (const float*)d_in[10], (const float*)d_in[15]};
  const float* gam[3]   = {(const float*)d_in[6], (const float*)d_in[11], (const float*)d_in[16]};
  const float* bet[3]   = {(const float*)d_in[7], (const float*)d_in[12], (const float*)d_in[17]};
  const float* Wc = (const float*)d_in[18];
  const float* bc = (const float*)d_in[19];
  float* out = (float*)d_out;

  const int N = N_NODES, E = N_EDGES;
  const float invN = 1.0f / (float)N;

  float* bufA = (float*)d_ws;
  float* bufB = bufA + (size_t)N * 128;
  float* bufC = bufB + (size_t)N * 128;
  int* deg    = (int*)(bufC + (size_t)N * 128);
  int* offs   = deg + N;
  int* cursor = offs + N + 1;
  int* esrc   = cursor + N;
  float* stats  = (float*)(esrc + E);
  float* sscale = stats + 256;
  float* sshift = sscale + 128;
  int* bsum     = (int*)(sshift + 128);  // up to 128 block sums

  // ---- CSR build ----
  hipMemsetAsync(deg, 0, N * sizeof(int), stream);
  k_hist<<<(E + 255) / 256, 256, 0, stream>>>(dst, deg, E);
  int nb = (N + 1023) / 1024;  // 98
  k_scan1<<<nb, 256, 0, stream>>>(deg, offs, bsum, N);
  k_scan2<<<1, 256, 0, stream>>>(bsum, nb);
  k_scan3<<<(N + 255) / 256, 256, 0, stream>>>(offs, cursor, bsum, N, E);
  k_scatter<<<(E + 255) / 256, 256, 0, stream>>>(src, dst, cursor, esrc, E);

  const int gemmBlocks = (N + 63) / 64;

  // ---- layer 0 (din=64) ----
  k_agg<64><<<(N * 16 + 255) / 256, 256, 0, stream>>>(x, offs, esrc, bufC, N);
  hipMemsetAsync(stats, 0, 256 * sizeof(float), stream);
  k_gemm2<<<gemmBlocks, 256, 0, stream>>>(x, Wself[0], bufC, Wngh[0], bself[0],
                                          bufA, stats, N, 64);
  k_bnfin<<<1, 128, 0, stream>>>(stats, gam[0], bet[0], sscale, sshift, invN);
  k_bnrelu<<<(N * 32 + 255) / 256, 256, 0, stream>>>(bufA, sscale, sshift, N * 32);

  // ---- layer 1 (din=128) ----
  k_agg<128><<<(N * 32 + 255) / 256, 256, 0, stream>>>(bufA, offs, esrc, bufC, N);
  hipMemsetAsync(stats, 0, 256 * sizeof(float), stream);
  k_gemm2<<<gemmBlocks, 256, 0, stream>>>(bufA, Wself[1], bufC, Wngh[1], bself[1],
                                          bufB, stats, N, 128);
  k_bnfin<<<1, 128, 0, stream>>>(stats, gam[1], bet[1], sscale, sshift, invN);
  k_bnrelu<<<(N * 32 + 255) / 256, 256, 0, stream>>>(bufB, sscale, sshift, N * 32);

  // ---- layer 2 (din=128) ----
  k_agg<128><<<(N * 32 + 255) / 256, 256, 0, stream>>>(bufB, offs, esrc, bufC, N);
  hipMemsetAsync(stats, 0, 256 * sizeof(float), stream);
  k_gemm2<<<gemmBlocks, 256, 0, stream>>>(bufB, Wself[2], bufC, Wngh[2], bself[2],
                                          bufA, stats, N, 128);
  k_bnfin<<<1, 128, 0, stream>>>(stats, gam[2], bet[2], sscale, sshift, invN);

  // ---- fused BN+ReLU+classifier ----
  k_final<<<(N + 3) / 4, 256, 0, stream>>>(bufA, sscale, sshift, Wc, bc, out, N);
}

// Round 2
// 596.049 us; speedup vs baseline: 1.4623x; 1.4623x over previous
//
#include <hip/hip_runtime.h>

// GraphSAGE x3 + BN(train stats) + ReLU + head. bf16 features/weights,
// fp32 accumulation (MFMA 16x16x32) and fp32 BN statistics.

#define N_NODES 100000
#define N_EDGES 1250000

typedef short bf16x8 __attribute__((ext_vector_type(8)));
typedef float f32x4 __attribute__((ext_vector_type(4)));
typedef unsigned short u16x8 __attribute__((ext_vector_type(8)));
typedef unsigned short u16x4 __attribute__((ext_vector_type(4)));

__device__ __forceinline__ float bf2f(unsigned short u) {
  union { unsigned int i; float f; } c; c.i = ((unsigned int)u) << 16; return c.f;
}
__device__ __forceinline__ unsigned short f2bf(float f) {
  union { float f; unsigned int i; } c; c.f = f;
  unsigned int r = (c.i + 0x7FFFu + ((c.i >> 16) & 1u)) >> 16;  // RNE
  return (unsigned short)r;
}

// ----------------- CSR build -----------------
__global__ void k_hist(const int* __restrict__ dst, int* __restrict__ deg, int E) {
  int i = blockIdx.x * blockDim.x + threadIdx.x;
  if (i < E) atomicAdd(&deg[dst[i]], 1);
}

__global__ void k_scan1(const int* __restrict__ deg, int* __restrict__ offs,
                        int* __restrict__ bsum, int n) {
  __shared__ int sh[256];
  int t = threadIdx.x;
  int base = blockIdx.x * 1024 + t * 4;
  int v0 = (base + 0 < n) ? deg[base + 0] : 0;
  int v1 = (base + 1 < n) ? deg[base + 1] : 0;
  int v2 = (base + 2 < n) ? deg[base + 2] : 0;
  int v3 = (base + 3 < n) ? deg[base + 3] : 0;
  int s = v0 + v1 + v2 + v3;
  sh[t] = s;
  __syncthreads();
  #pragma unroll
  for (int off = 1; off < 256; off <<= 1) {
    int x = (t >= off) ? sh[t - off] : 0;
    __syncthreads();
    sh[t] += x;
    __syncthreads();
  }
  int run = sh[t] - s;
  if (base + 0 < n) offs[base + 0] = run; run += v0;
  if (base + 1 < n) offs[base + 1] = run; run += v1;
  if (base + 2 < n) offs[base + 2] = run; run += v2;
  if (base + 3 < n) offs[base + 3] = run;
  if (t == 255) bsum[blockIdx.x] = sh[255];
}

__global__ void k_scan2(int* __restrict__ bsum, int nb) {
  __shared__ int sh[256];
  int t = threadIdx.x;
  int v = (t < nb) ? bsum[t] : 0;
  sh[t] = v;
  __syncthreads();
  #pragma unroll
  for (int off = 1; off < 256; off <<= 1) {
    int x = (t >= off) ? sh[t - off] : 0;
    __syncthreads();
    sh[t] += x;
    __syncthreads();
  }
  if (t < nb) bsum[t] = sh[t] - v;
}

__global__ void k_scan3(int* __restrict__ offs, int* __restrict__ cursor,
                        const int* __restrict__ bsum, int n, int E) {
  int i = blockIdx.x * blockDim.x + threadIdx.x;
  if (i < n) {
    int v = offs[i] + bsum[i >> 10];
    offs[i] = v;
    cursor[i] = v;
  }
  if (i == 0) offs[n] = E;
}

__global__ void k_scatter(const int* __restrict__ src, const int* __restrict__ dst,
                          int* __restrict__ cursor, int* __restrict__ esrc, int E) {
  int i = blockIdx.x * blockDim.x + threadIdx.x;
  if (i < E) {
    int p = atomicAdd(&cursor[dst[i]], 1);
    esrc[p] = src[i];
  }
}

// ----------------- fp32 -> bf16 convert -----------------
__global__ void k_f2bf(const float* __restrict__ in, unsigned short* __restrict__ out, int n4) {
  int i = blockIdx.x * blockDim.x + threadIdx.x;
  if (i >= n4) return;
  float4 v = ((const float4*)in)[i];
  u16x4 o;
  o.x = f2bf(v.x); o.y = f2bf(v.y); o.z = f2bf(v.z); o.w = f2bf(v.w);
  ((u16x4*)out)[i] = o;
}

// ----------------- weight prep: convert + transpose -----------------
// wt layout (bf16): [0]=W0s^T(128x64) [8192]=W0n^T [16384]=W1s^T(128x128)
// [32768]=W1n^T [49152]=W2s^T [65536]=W2n^T   (W^T[c][k] = W[k][c])
__global__ void k_wprep(const float* __restrict__ W0s, const float* __restrict__ W0n,
                        const float* __restrict__ W1s, const float* __restrict__ W1n,
                        const float* __restrict__ W2s, const float* __restrict__ W2n,
                        unsigned short* __restrict__ wt) {
  int i = blockIdx.x * blockDim.x + threadIdx.x;
  if (i >= 81920) return;
  if (i < 16384) {
    const float* W = (i < 8192) ? W0s : W0n;
    unsigned short* o = wt + (i < 8192 ? 0 : 8192);
    int j = i & 8191;
    int c = j >> 6, k = j & 63;          // din=64
    o[j] = f2bf(W[k * 128 + c]);
  } else {
    int j = i - 16384;
    int sel = j >> 14;
    j &= 16383;
    const float* W = (sel == 0) ? W1s : (sel == 1) ? W1n : (sel == 2) ? W2s : W2n;
    unsigned short* o = wt + 16384 + sel * 16384;
    int c = j >> 7, k = j & 127;         // din=128
    o[j] = f2bf(W[k * 128 + c]);
  }
}

// ----------------- mean aggregation (bf16 gather, fp32 accumulate) ---------
template <int DIM>
__global__ void k_agg(const unsigned short* __restrict__ h, const int* __restrict__ offs,
                      const int* __restrict__ esrc, unsigned short* __restrict__ neigh, int n) {
  const int G = DIM / 8;
  int tid = blockIdx.x * blockDim.x + threadIdx.x;
  int node = tid / G;
  int f = tid % G;
  if (node >= n) return;
  int s = offs[node], e = offs[node + 1];
  float acc[8] = {0.f, 0.f, 0.f, 0.f, 0.f, 0.f, 0.f, 0.f};
  for (int j = s; j < e; j++) {
    int sn = esrc[j];
    u16x8 v = *(const u16x8*)&h[(size_t)sn * DIM + 8 * f];
    #pragma unroll
    for (int k = 0; k < 8; k++) acc[k] += bf2f(v[k]);
  }
  float inv = 1.0f / fmaxf((float)(e - s), 1.0f);
  u16x8 o;
  #pragma unroll
  for (int k = 0; k < 8; k++) o[k] = f2bf(acc[k] * inv);
  *(u16x8*)&neigh[(size_t)node * DIM + 8 * f] = o;
}

// ----------------- MFMA GEMM: C = A1@W1 + A2@W2 + bias (+BN stats) --------
// Block: 128 rows x 128 cols, 256 threads = 4 waves, wave w owns 32 rows.
// K-step 32 over both halves. LDS tiles padded to stride 40 bf16.
__global__ __launch_bounds__(256) void k_gemm_mfma(
    const unsigned short* __restrict__ A1, const unsigned short* __restrict__ W1t,
    const unsigned short* __restrict__ A2, const unsigned short* __restrict__ W2t,
    const float* __restrict__ bias, unsigned short* __restrict__ C,
    float* __restrict__ stats, int M, int din) {
  __shared__ unsigned short As[128 * 40];
  __shared__ unsigned short Bs[128 * 40];
  __shared__ float redS[4 * 128];
  __shared__ float redQ[4 * 128];

  int t = threadIdx.x;
  int lane = t & 63, w = t >> 6;
  int l15 = lane & 15, quad = lane >> 4;
  int row0 = blockIdx.x * 128;

  f32x4 acc[2][8];
  #pragma unroll
  for (int rt = 0; rt < 2; rt++)
    #pragma unroll
    for (int ct = 0; ct < 8; ct++) acc[rt][ct] = (f32x4){0.f, 0.f, 0.f, 0.f};

  for (int half = 0; half < 2; half++) {
    const unsigned short* A = half ? A2 : A1;
    const unsigned short* Wt = half ? W2t : W1t;
    for (int k0 = 0; k0 < din; k0 += 32) {
      __syncthreads();
      // stage A rows (128 x 32) and W^T rows (=out cols) (128 x 32)
      #pragma unroll
      for (int i = 0; i < 2; i++) {
        int idx = t + 256 * i;       // 0..511
        int r = idx >> 2, part = idx & 3;
        int row = row0 + r;
        u16x8 v = (u16x8){0, 0, 0, 0, 0, 0, 0, 0};
        if (row < M) v = *(const u16x8*)&A[(size_t)row * din + k0 + part * 8];
        *(u16x8*)&As[r * 40 + part * 8] = v;
        *(u16x8*)&Bs[r * 40 + part * 8] = *(const u16x8*)&Wt[(size_t)r * din + k0 + part * 8];
      }
      __syncthreads();
      bf16x8 af[2], bfr[8];
      #pragma unroll
      for (int rt = 0; rt < 2; rt++)
        af[rt] = *(const bf16x8*)&As[(w * 32 + rt * 16 + l15) * 40 + quad * 8];
      #pragma unroll
      for (int ct = 0; ct < 8; ct++)
        bfr[ct] = *(const bf16x8*)&Bs[(ct * 16 + l15) * 40 + quad * 8];
      #pragma unroll
      for (int rt = 0; rt < 2; rt++)
        #pragma unroll
        for (int ct = 0; ct < 8; ct++)
          acc[rt][ct] = __builtin_amdgcn_mfma_f32_16x16x32_bf16(af[rt], bfr[ct], acc[rt][ct], 0, 0, 0);
    }
  }

  // epilogue: bias, bf16 store, BN stat partials
  float bcol[8], ls[8], lq[8];
  #pragma unroll
  for (int ct = 0; ct < 8; ct++) {
    bcol[ct] = bias[ct * 16 + l15];
    ls[ct] = 0.f; lq[ct] = 0.f;
  }
  #pragma unroll
  for (int rt = 0; rt < 2; rt++) {
    #pragma unroll
    for (int r = 0; r < 4; r++) {
      int row = row0 + w * 32 + rt * 16 + quad * 4 + r;
      if (row < M) {
        #pragma unroll
        for (int ct = 0; ct < 8; ct++) {
          float v = acc[rt][ct][r] + bcol[ct];
          C[(size_t)row * 128 + ct * 16 + l15] = f2bf(v);
          ls[ct] += v; lq[ct] += v * v;
        }
      }
    }
  }
  #pragma unroll
  for (int ct = 0; ct < 8; ct++) {
    ls[ct] += __shfl_xor(ls[ct], 16); ls[ct] += __shfl_xor(ls[ct], 32);
    lq[ct] += __shfl_xor(lq[ct], 16); lq[ct] += __shfl_xor(lq[ct], 32);
  }
  if (quad == 0) {
    #pragma unroll
    for (int ct = 0; ct < 8; ct++) {
      redS[w * 128 + ct * 16 + l15] = ls[ct];
      redQ[w * 128 + ct * 16 + l15] = lq[ct];
    }
  }
  __syncthreads();
  if (t < 128) {
    float s = redS[t] + redS[128 + t] + redS[256 + t] + redS[384 + t];
    float q = redQ[t] + redQ[128 + t] + redQ[256 + t] + redQ[384 + t];
    atomicAdd(&stats[t], s);
    atomicAdd(&stats[128 + t], q);
  }
}

// ----------------- BN finalize -----------------
__global__ void k_bnfin(const float* __restrict__ stats, const float* __restrict__ gamma,
                        const float* __restrict__ beta, float* __restrict__ sscale,
                        float* __restrict__ sshift, float invN) {
  int c = threadIdx.x;
  float mu = stats[c] * invN;
  float var = stats[128 + c] * invN - mu * mu;
  float rs = rsqrtf(var + 1e-5f);
  float s = gamma[c] * rs;
  sscale[c] = s;
  sshift[c] = beta[c] - mu * s;
}

// ----------------- BN apply + ReLU (bf16, in place) -----------------
__global__ void k_bnrelu16(unsigned short* __restrict__ h, const float* __restrict__ sscale,
                           const float* __restrict__ sshift, int total8) {
  int i = blockIdx.x * blockDim.x + threadIdx.x;
  if (i >= total8) return;
  int c8 = (i & 15) * 8;
  u16x8 v = ((u16x8*)h)[i];
  #pragma unroll
  for (int k = 0; k < 8; k++) {
    float f = fmaxf(fmaf(bf2f(v[k]), sscale[c8 + k], sshift[c8 + k]), 0.f);
    v[k] = f2bf(f);
  }
  ((u16x8*)h)[i] = v;
}

// ----------------- fused BN + ReLU + classifier -----------------
__global__ void k_final(const unsigned short* __restrict__ h, const float* __restrict__ sscale,
                        const float* __restrict__ sshift, const float* __restrict__ Wc,
                        const float* __restrict__ bc, float* __restrict__ out, int n) {
  int lane = threadIdx.x & 63;
  int row = blockIdx.x * (blockDim.x >> 6) + (threadIdx.x >> 6);
  if (row >= n) return;
  float acc0 = 0.f, acc1 = 0.f;
  #pragma unroll
  for (int m = 0; m < 2; m++) {
    int c = lane + 64 * m;
    float v = bf2f(h[(size_t)row * 128 + c]);
    v = fmaxf(fmaf(v, sscale[c], sshift[c]), 0.f);
    acc0 += v * Wc[c * 2 + 0];
    acc1 += v * Wc[c * 2 + 1];
  }
  #pragma unroll
  for (int off = 32; off > 0; off >>= 1) {
    acc0 += __shfl_down(acc0, off);
    acc1 += __shfl_down(acc1, off);
  }
  if (lane == 0) {
    out[row * 2 + 0] = acc0 + bc[0];
    out[row * 2 + 1] = acc1 + bc[1];
  }
}

extern "C" void kernel_launch(void* const* d_in, const int* in_sizes, int n_in,
                              void* d_out, int out_size, void* d_ws, size_t ws_size,
                              hipStream_t stream) {
  const float* x   = (const float*)d_in[0];
  const int* src   = (const int*)d_in[1];
  const int* dst   = (const int*)d_in[2];
  const float* Wself[3] = {(const float*)d_in[3], (const float*)d_in[8],  (const float*)d_in[13]};
  const float* bself[3] = {(const float*)d_in[4], (const float*)d_in[9],  (const float*)d_in[14]};
  const float* Wngh[3]  = {(const float*)d_in[5], (const float*)d_in[10], (const float*)d_in[15]};
  const float* gam[3]   = {(const float*)d_in[6], (const float*)d_in[11], (const float*)d_in[16]};
  const float* bet[3]   = {(const float*)d_in[7], (const float*)d_in[12], (const float*)d_in[17]};
  const float* Wc = (const float*)d_in[18];
  const float* bc = (const float*)d_in[19];
  float* out = (float*)d_out;

  const int N = N_NODES, E = N_EDGES;
  const float invN = 1.0f / (float)N;

  unsigned short* x16 = (unsigned short*)d_ws;        // N*64
  unsigned short* b0  = x16 + (size_t)N * 64;         // N*128 (neigh)
  unsigned short* b1  = b0 + (size_t)N * 128;
  unsigned short* b2  = b1 + (size_t)N * 128;
  unsigned short* wt  = b2 + (size_t)N * 128;         // 81920
  int* deg    = (int*)(wt + 81920);
  int* offs   = deg + N;
  int* cursor = offs + N + 1;
  int* esrc   = cursor + N;
  float* stats  = (float*)(esrc + E);
  float* sscale = stats + 256;
  float* sshift = sscale + 128;
  int* bsum     = (int*)(sshift + 128);

  // ---- CSR build ----
  hipMemsetAsync(deg, 0, N * sizeof(int), stream);
  k_hist<<<(E + 255) / 256, 256, 0, stream>>>(dst, deg, E);
  int nb = (N + 1023) / 1024;
  k_scan1<<<nb, 256, 0, stream>>>(deg, offs, bsum, N);
  k_scan2<<<1, 256, 0, stream>>>(bsum, nb);
  k_scan3<<<(N + 255) / 256, 256, 0, stream>>>(offs, cursor, bsum, N, E);
  k_scatter<<<(E + 255) / 256, 256, 0, stream>>>(src, dst, cursor, esrc, E);

  // ---- conversions ----
  k_f2bf<<<(N * 16 + 255) / 256, 256, 0, stream>>>(x, x16, N * 16);
  k_wprep<<<(81920 + 255) / 256, 256, 0, stream>>>(Wself[0], Wngh[0], Wself[1], Wngh[1],
                                                   Wself[2], Wngh[2], wt);

  const int gemmBlocks = (N + 127) / 128;

  // ---- layer 0 (din=64) ----
  k_agg<64><<<(N * 8 + 255) / 256, 256, 0, stream>>>(x16, offs, esrc, b0, N);
  hipMemsetAsync(stats, 0, 256 * sizeof(float), stream);
  k_gemm_mfma<<<gemmBlocks, 256, 0, stream>>>(x16, wt + 0, b0, wt + 8192, bself[0],
                                              b1, stats, N, 64);
  k_bnfin<<<1, 128, 0, stream>>>(stats, gam[0], bet[0], sscale, sshift, invN);
  k_bnrelu16<<<(N * 16 + 255) / 256, 256, 0, stream>>>(b1, sscale, sshift, N * 16);

  // ---- layer 1 (din=128) ----
  k_agg<128><<<(N * 16 + 255) / 256, 256, 0, stream>>>(b1, offs, esrc, b0, N);
  hipMemsetAsync(stats, 0, 256 * sizeof(float), stream);
  k_gemm_mfma<<<gemmBlocks, 256, 0, stream>>>(b1, wt + 16384, b0, wt + 32768, bself[1],
                                              b2, stats, N, 128);
  k_bnfin<<<1, 128, 0, stream>>>(stats, gam[1], bet[1], sscale, sshift, invN);
  k_bnrelu16<<<(N * 16 + 255) / 256, 256, 0, stream>>>(b2, sscale, sshift, N * 16);

  // ---- layer 2 (din=128) ----
  k_agg<128><<<(N * 16 + 255) / 256, 256, 0, stream>>>(b2, offs, esrc, b0, N);
  hipMemsetAsync(stats, 0, 256 * sizeof(float), stream);
  k_gemm_mfma<<<gemmBlocks, 256, 0, stream>>>(b2, wt + 49152, b0, wt + 65536, bself[2],
                                              b1, stats, N, 128);
  k_bnfin<<<1, 128, 0, stream>>>(stats, gam[2], bet[2], sscale, sshift, invN);

  // ---- fused BN+ReLU+classifier ----
  k_final<<<(N + 3) / 4, 256, 0, stream>>>(b1, sscale, sshift, Wc, bc, out, N);
}